// Round 5
// baseline (231.586 us; speedup 1.0000x reference)
//
#include <hip/hip_runtime.h>

#define B_SZ 1024
#define S_SZ 200
#define D_SZ 64
#define NI_SZ 4
#define E_SZ 256

using u16 = unsigned short;
using u32 = unsigned int;
typedef short  sh8    __attribute__((ext_vector_type(8)));
typedef __bf16 bf16x8 __attribute__((ext_vector_type(8)));
typedef float  f32x4  __attribute__((ext_vector_type(4)));

__device__ __forceinline__ u16 f2bf(float x) {          // RNE f32 -> bf16 bits
  u32 u = __float_as_uint(x);
  u += 0x7FFFu + ((u >> 16) & 1u);
  return (u16)(u >> 16);
}
__device__ __forceinline__ float bf2f(u16 h) {
  return __uint_as_float(((u32)h) << 16);
}
// swizzled LDS tile access: row-major [R][64] bf16 (128 B rows), byte ^= (row&7)<<4
__device__ __forceinline__ sh8 ldsr(const u16* arr, int row, int kshort) {
  const int idx = row * 64 + (kshort ^ ((row & 7) << 3));
  return *(const sh8*)(arr + idx);
}
__device__ __forceinline__ bf16x8 ldsw(const u16* arr, int row, int kshort) {
  return __builtin_bit_cast(bf16x8, ldsr(arr, row, kshort));
}
__device__ __forceinline__ void stsw(u16* arr, int row, int c, sh8 v) {
  *(sh8*)(arr + row * 64 + 8 * (c ^ (row & 7))) = v;
}

// ---------------- K1: w_capsule -> bf16 ----------------
__global__ __launch_bounds__(256) void wconv_kernel(
    const float* __restrict__ W, u16* __restrict__ Wb)
{
  const int idx = blockIdx.x * 256 + threadIdx.x;     // 8-float units
  if (idx >= S_SZ * E_SZ * D_SZ / 8) return;
  const float4 a = *(const float4*)(W + (size_t)idx * 8);
  const float4 b = *(const float4*)(W + (size_t)idx * 8 + 4);
  sh8 r;
  r[0] = (short)f2bf(a.x); r[1] = (short)f2bf(a.y);
  r[2] = (short)f2bf(a.z); r[3] = (short)f2bf(a.w);
  r[4] = (short)f2bf(b.x); r[5] = (short)f2bf(b.y);
  r[6] = (short)f2bf(b.z); r[7] = (short)f2bf(b.w);
  *(sh8*)(Wb + (size_t)idx * 8) = r;
}

// ---------------- K2: fused profile + gather + adj MFMA (+ item_bs side output) ----------------
// adj[b,i,j] = sigmoid(sum_d (item[i,d]*prof[d]) * item[j,d]) * m_i * m_j
__global__ __launch_bounds__(256, 4) void adj_fused(
    const int* __restrict__ uid, const int* __restrict__ age,
    const int* __restrict__ gender, const int* __restrict__ occup,
    const float* __restrict__ U, const float* __restrict__ AT,
    const float* __restrict__ GT, const float* __restrict__ OT,
    const int* __restrict__ mid_his, const float* __restrict__ mask,
    const float* __restrict__ memb,
    u16* __restrict__ item_bs, float* __restrict__ adj)
{
  const int b = blockIdx.x;
  __shared__ u16   Hs[208 * 64];   // item tile, swizzled
  __shared__ float Ms[208];
  __shared__ int   midS[S_SZ];
  __shared__ float pS[D_SZ];
  const int tid = threadIdx.x;

  if (tid < 208) Ms[tid] = (tid < S_SZ) ? mask[b * S_SZ + tid] : 0.f;
  if (tid < S_SZ) midS[tid] = mid_his[b * S_SZ + tid];
  if (tid < D_SZ) {
    float v = U[(size_t)uid[b]    * D_SZ + tid]
            + GT[(size_t)gender[b] * D_SZ + tid]
            + AT[(size_t)age[b]    * D_SZ + tid]
            + OT[(size_t)occup[b]  * D_SZ + tid];
    pS[tid] = 0.25f * v;
  }
  __syncthreads();

  // gather mid_emb rows -> bf16 item tile (LDS, swizzled) + global item_bs
  for (int idx = tid; idx < S_SZ * 8; idx += 256) {
    const int row = idx >> 3, c = idx & 7;
    const float m = Ms[row];
    const float* src = memb + (size_t)midS[row] * D_SZ + c * 8;
    const float4 a = *(const float4*)(src);
    const float4 d = *(const float4*)(src + 4);
    sh8 v;
    v[0] = (short)f2bf(a.x * m); v[1] = (short)f2bf(a.y * m);
    v[2] = (short)f2bf(a.z * m); v[3] = (short)f2bf(a.w * m);
    v[4] = (short)f2bf(d.x * m); v[5] = (short)f2bf(d.y * m);
    v[6] = (short)f2bf(d.z * m); v[7] = (short)f2bf(d.w * m);
    stsw(Hs, row, c, v);
    *(sh8*)(item_bs + ((size_t)b * S_SZ + row) * D_SZ + c * 8) = v;
  }
  if (tid < 64) {   // zero-pad rows 200..207
    sh8 z = {0,0,0,0,0,0,0,0};
    stsw(Hs, S_SZ + (tid >> 3), tid & 7, z);
  }
  __syncthreads();

  const int w = tid >> 6, l = tid & 63;
  const int lr = l & 15, lg = l >> 4;
  float pvA[8], pvB[8];
  #pragma unroll
  for (int j = 0; j < 8; j++) { pvA[j] = pS[lg * 8 + j]; pvB[j] = pS[32 + lg * 8 + j]; }

  float* outb = adj + (size_t)b * S_SZ * S_SZ;
  for (int mt = 0; mt < 13; mt++) {
    const int arow = mt * 16 + lr;
    const sh8 r0 = ldsr(Hs, arow, lg * 8);
    const sh8 r1 = ldsr(Hs, arow, 32 + lg * 8);
    sh8 h0, h1;
    #pragma unroll
    for (int j = 0; j < 8; j++) {
      h0[j] = (short)f2bf(bf2f((u16)r0[j]) * pvA[j]);
      h1[j] = (short)f2bf(bf2f((u16)r1[j]) * pvB[j]);
    }
    const bf16x8 a0 = __builtin_bit_cast(bf16x8, h0);
    const bf16x8 a1 = __builtin_bit_cast(bf16x8, h1);
    for (int nt = w; nt < 13; nt += 4) {
      const int brow = nt * 16 + lr;
      const bf16x8 b0 = ldsw(Hs, brow, lg * 8);
      const bf16x8 b1 = ldsw(Hs, brow, 32 + lg * 8);
      f32x4 acc = {0.f, 0.f, 0.f, 0.f};
      acc = __builtin_amdgcn_mfma_f32_16x16x32_bf16(a0, b0, acc, 0, 0, 0);
      acc = __builtin_amdgcn_mfma_f32_16x16x32_bf16(a1, b1, acc, 0, 0, 0);
      const int n = nt * 16 + lr;
      const float mj = Ms[n];
      #pragma unroll
      for (int r = 0; r < 4; r++) {
        const int m = mt * 16 + lg * 4 + r;
        if (m < S_SZ && n < S_SZ) {
          const float sg = 1.f / (1.f + __expf(-acc[r]));
          __builtin_nontemporal_store(sg * Ms[m] * mj, &outb[(size_t)m * S_SZ + n]);
        }
      }
    }
  }
}

// ---------------- K3: hat via MFMA, bf16 output ----------------
// hat[b,kc,s,d] = sum_k item[b,s,k] * W[s, kc*64+d, k]
__global__ __launch_bounds__(256, 4) void hat_mfma(
    const u16* __restrict__ item_bs, const u16* __restrict__ Wb,
    u16* __restrict__ hatb)
{
  const int s  = blockIdx.y;
  const int b0 = blockIdx.x * 64;
  __shared__ u16 As[64 * 64];     // item rows (A-side), 8 KB
  __shared__ u16 Ws_[256 * 64];   // W[s] (B-side), 32 KB
  const int tid = threadIdx.x;

  for (int idx = tid; idx < 64 * 8; idx += 256) {
    const int row = idx >> 3, c = idx & 7;
    const sh8 v = *(const sh8*)(item_bs + ((size_t)(b0 + row) * S_SZ + s) * D_SZ + c * 8);
    stsw(As, row, c, v);
  }
  for (int idx = tid; idx < 256 * 8; idx += 256) {
    const int row = idx >> 3, c = idx & 7;
    const sh8 v = *(const sh8*)(Wb + ((size_t)s * E_SZ + row) * D_SZ + c * 8);
    stsw(Ws_, row, c, v);
  }
  __syncthreads();

  const int w = tid >> 6, l = tid & 63;
  const int lr = l & 15, lg = l >> 4;

  f32x4 acc[4][4];
  #pragma unroll
  for (int mt = 0; mt < 4; mt++)
    #pragma unroll
    for (int nt = 0; nt < 4; nt++) acc[mt][nt] = (f32x4){0.f, 0.f, 0.f, 0.f};

  #pragma unroll
  for (int ks = 0; ks < 2; ks++) {
    bf16x8 af[4], bf_[4];
    #pragma unroll
    for (int mt = 0; mt < 4; mt++)
      af[mt] = ldsw(As, mt * 16 + lr, ks * 32 + lg * 8);
    #pragma unroll
    for (int nt = 0; nt < 4; nt++)
      bf_[nt] = ldsw(Ws_, w * 64 + nt * 16 + lr, ks * 32 + lg * 8);
    #pragma unroll
    for (int mt = 0; mt < 4; mt++)
      #pragma unroll
      for (int nt = 0; nt < 4; nt++)
        acc[mt][nt] = __builtin_amdgcn_mfma_f32_16x16x32_bf16(af[mt], bf_[nt], acc[mt][nt], 0, 0, 0);
  }

  // e = w*64 + nt*16 + lr  ->  kc = w, d = nt*16 + lr
  #pragma unroll
  for (int mt = 0; mt < 4; mt++) {
    #pragma unroll
    for (int r = 0; r < 4; r++) {
      const int bb = b0 + mt * 16 + lg * 4 + r;
      u16* dst = hatb + (((size_t)bb * NI_SZ + w) * S_SZ + s) * D_SZ;
      #pragma unroll
      for (int nt = 0; nt < 4; nt++)
        dst[nt * 16 + lr] = f2bf(acc[mt][nt][r]);
    }
  }
}

// ---------------- K4: dynamic routing (bf16 hat, register-resident) ----------------
__device__ __forceinline__ float rlane(float v, int l) {
  return __int_as_float(__builtin_amdgcn_readlane(__float_as_int(v), l));
}

__global__ __launch_bounds__(1024, 4) void route_kernel(
    const u16* __restrict__ hatb, const float* __restrict__ mask,
    float* __restrict__ out)
{
  const int b = blockIdx.x;
  const int t = threadIdx.x;
  const int w = t >> 6, lane = t & 63;
  const int k = w >> 2, q = w & 3;
  __shared__ float cwS[NI_SZ][212];
  __shared__ float partS[NI_SZ][4][D_SZ];

  const float msv = (lane < 50) ? mask[b * S_SZ + q * 50 + lane] : 0.f;

  float hr[50];
  const u16* hg = hatb + (((size_t)b * NI_SZ + k) * S_SZ + q * 50) * D_SZ + lane;
  #pragma unroll
  for (int j = 0; j < 50; j++) hr[j] = bf2f(hg[j * D_SZ]);
  #pragma unroll
  for (int j = 0; j < 50; j++) asm volatile("" : "+v"(hr[j]));

  const int jj = __brev(lane) >> 26;

  for (int iter = 0; iter < 3; ++iter) {
    float swv;
    if (iter == 0) {
      swv = 0.25f * msv;
    } else {
      const int sidx = q * 50 + (lane < 50 ? lane : 49);
      const float a0 = cwS[0][sidx], a1 = cwS[1][sidx],
                  a2 = cwS[2][sidx], a3 = cwS[3][sidx];
      const float mx = fmaxf(fmaxf(a0, a1), fmaxf(a2, a3));
      const float e0 = __expf(a0 - mx), e1 = __expf(a1 - mx),
                  e2 = __expf(a2 - mx), e3 = __expf(a3 - mx);
      const float ek = (k == 0) ? e0 : (k == 1) ? e1 : (k == 2) ? e2 : e3;
      const float inv = 1.f / (e0 + e1 + e2 + e3);
      swv = (msv == 0.f) ? 0.f : ek * inv;
    }

    float c0 = 0.f, c1 = 0.f, c2 = 0.f, c3 = 0.f;
    #pragma unroll
    for (int j = 0; j < 48; j += 4) {
      c0 = fmaf(rlane(swv, j + 0), hr[j + 0], c0);
      c1 = fmaf(rlane(swv, j + 1), hr[j + 1], c1);
      c2 = fmaf(rlane(swv, j + 2), hr[j + 2], c2);
      c3 = fmaf(rlane(swv, j + 3), hr[j + 3], c3);
    }
    c0 = fmaf(rlane(swv, 48), hr[48], c0);
    c1 = fmaf(rlane(swv, 49), hr[49], c1);
    partS[k][q][lane] = (c0 + c2) + (c1 + c3);
    __syncthreads();

    const float cap = partS[k][0][lane] + partS[k][1][lane]
                    + partS[k][2][lane] + partS[k][3][lane];
    float n = cap * cap;
    #pragma unroll
    for (int off = 32; off; off >>= 1) n += __shfl_xor(n, off);
    const float f = n / (1.f + n) * rsqrtf(n + 1e-9f);
    const float capd = cap * f;

    if (iter < 2) {
      float p[32];
      {
        const int bit = lane & 1;
        #pragma unroll
        for (int j = 0; j < 32; j++) {
          const float lo = hr[j] * capd;
          const float hi = (j + 32 < 50) ? hr[j + 32] * capd : 0.f;
          const float send = bit ? lo : hi;
          const float keep = bit ? hi : lo;
          p[j] = keep + __shfl_xor(send, 1);
        }
      }
      #pragma unroll
      for (int r = 1; r < 6; r++) {
        const int dist = 1 << r;
        const int half = 32 >> r;
        const int bit = (lane >> r) & 1;
        #pragma unroll
        for (int j = 0; j < 32; j++) {
          if (j < half) {
            const float send = bit ? p[j] : p[j + half];
            const float keep = bit ? p[j + half] : p[j];
            p[j] = keep + __shfl_xor(send, dist);
          }
        }
      }
      if (jj < 50) {
        if (iter == 0) cwS[k][q * 50 + jj] = p[0];
        else           cwS[k][q * 50 + jj] += p[0];
      }
      __syncthreads();
    } else if (q == 0) {
      out[((size_t)b * NI_SZ + k) * D_SZ + lane] = capd;
    }
  }
}

extern "C" void kernel_launch(void* const* d_in, const int* in_sizes, int n_in,
                              void* d_out, int out_size, void* d_ws, size_t ws_size,
                              hipStream_t stream)
{
  const int*   uid     = (const int*)d_in[0];
  const int*   age     = (const int*)d_in[1];
  const int*   gender  = (const int*)d_in[2];
  const int*   occup   = (const int*)d_in[3];
  const int*   mid_his = (const int*)d_in[4];
  const float* mask    = (const float*)d_in[5];
  const float* U       = (const float*)d_in[6];
  const float* AT      = (const float*)d_in[7];
  const float* GT      = (const float*)d_in[8];
  const float* OT      = (const float*)d_in[9];
  const float* ME      = (const float*)d_in[10];
  const float* WC      = (const float*)d_in[11];

  float* out  = (float*)d_out;
  float* adj  = out + B_SZ * NI_SZ * D_SZ;

  char* ws = (char*)d_ws;
  u16*   item_bs = (u16*)ws;                                 // 26.2 MB
  u16*   Wb      = (u16*)(ws + 26214400);                    // 6.55 MB
  u16*   hatb    = (u16*)(ws + 26214400 + 6553600);          // 104.9 MB

  wconv_kernel<<<(S_SZ * E_SZ * D_SZ / 8 + 255) / 256, 256, 0, stream>>>(WC, Wb);
  adj_fused<<<B_SZ, 256, 0, stream>>>(uid, age, gender, occup, U, AT, GT, OT,
                                      mid_his, mask, ME, item_bs, adj);
  hat_mfma<<<dim3(16, S_SZ), 256, 0, stream>>>(item_bs, Wb, hatb);
  route_kernel<<<B_SZ, 1024, 0, stream>>>(hatb, mask, out);
}

// Round 6
// 169.696 us; speedup vs baseline: 1.3647x; 1.3647x over previous
//
#include <hip/hip_runtime.h>

#define B_SZ 1024
#define S_SZ 200
#define D_SZ 64
#define NI_SZ 4
#define E_SZ 256

using u16 = unsigned short;
using u32 = unsigned int;
typedef short  sh8    __attribute__((ext_vector_type(8)));
typedef __bf16 bf16x8 __attribute__((ext_vector_type(8)));
typedef float  f32x4  __attribute__((ext_vector_type(4)));

__device__ __forceinline__ u16 f2bf(float x) {          // RNE f32 -> bf16 bits
  u32 u = __float_as_uint(x);
  u += 0x7FFFu + ((u >> 16) & 1u);
  return (u16)(u >> 16);
}
__device__ __forceinline__ float bf2f(u16 h) {
  return __uint_as_float(((u32)h) << 16);
}
// swizzled LDS tile access: row-major [R][64] bf16 (128 B rows), byte ^= (row&7)<<4
__device__ __forceinline__ sh8 ldsr(const u16* arr, int row, int kshort) {
  const int idx = row * 64 + (kshort ^ ((row & 7) << 3));
  return *(const sh8*)(arr + idx);
}
__device__ __forceinline__ bf16x8 ldsw(const u16* arr, int row, int kshort) {
  return __builtin_bit_cast(bf16x8, ldsr(arr, row, kshort));
}
__device__ __forceinline__ void stsw(u16* arr, int row, int c, sh8 v) {
  *(sh8*)(arr + row * 64 + 8 * (c ^ (row & 7))) = v;
}

// ---------------- K1: w_capsule -> bf16 ----------------
__global__ __launch_bounds__(256) void wconv_kernel(
    const float* __restrict__ W, u16* __restrict__ Wb)
{
  const int idx = blockIdx.x * 256 + threadIdx.x;     // 8-float units
  if (idx >= S_SZ * E_SZ * D_SZ / 8) return;
  const float4 a = *(const float4*)(W + (size_t)idx * 8);
  const float4 b = *(const float4*)(W + (size_t)idx * 8 + 4);
  sh8 r;
  r[0] = (short)f2bf(a.x); r[1] = (short)f2bf(a.y);
  r[2] = (short)f2bf(a.z); r[3] = (short)f2bf(a.w);
  r[4] = (short)f2bf(b.x); r[5] = (short)f2bf(b.y);
  r[6] = (short)f2bf(b.z); r[7] = (short)f2bf(b.w);
  *(sh8*)(Wb + (size_t)idx * 8) = r;
}

// ---------------- K2: fused profile + gather + adj MFMA (+ item_bs side output) ----------------
// adj[b,i,j] = sigmoid(sum_d (item[i,d]*prof[d]) * item[j,d]) * m_i * m_j
__global__ __launch_bounds__(256, 4) void adj_fused(
    const int* __restrict__ uid, const int* __restrict__ age,
    const int* __restrict__ gender, const int* __restrict__ occup,
    const float* __restrict__ U, const float* __restrict__ AT,
    const float* __restrict__ GT, const float* __restrict__ OT,
    const int* __restrict__ mid_his, const float* __restrict__ mask,
    const float* __restrict__ memb,
    u16* __restrict__ item_bs, float* __restrict__ adj)
{
  const int b = blockIdx.x;
  __shared__ u16   Hs[208 * 64];   // item tile, swizzled
  __shared__ float Ms[208];
  __shared__ int   midS[S_SZ];
  __shared__ float pS[D_SZ];
  const int tid = threadIdx.x;

  if (tid < 208) Ms[tid] = (tid < S_SZ) ? mask[b * S_SZ + tid] : 0.f;
  if (tid < S_SZ) midS[tid] = mid_his[b * S_SZ + tid];
  if (tid < D_SZ) {
    float v = U[(size_t)uid[b]    * D_SZ + tid]
            + GT[(size_t)gender[b] * D_SZ + tid]
            + AT[(size_t)age[b]    * D_SZ + tid]
            + OT[(size_t)occup[b]  * D_SZ + tid];
    pS[tid] = 0.25f * v;
  }
  __syncthreads();

  // gather mid_emb rows -> bf16 item tile (LDS, swizzled) + global item_bs
  for (int idx = tid; idx < S_SZ * 8; idx += 256) {
    const int row = idx >> 3, c = idx & 7;
    const float m = Ms[row];
    const float* src = memb + (size_t)midS[row] * D_SZ + c * 8;
    const float4 a = *(const float4*)(src);
    const float4 d = *(const float4*)(src + 4);
    sh8 v;
    v[0] = (short)f2bf(a.x * m); v[1] = (short)f2bf(a.y * m);
    v[2] = (short)f2bf(a.z * m); v[3] = (short)f2bf(a.w * m);
    v[4] = (short)f2bf(d.x * m); v[5] = (short)f2bf(d.y * m);
    v[6] = (short)f2bf(d.z * m); v[7] = (short)f2bf(d.w * m);
    stsw(Hs, row, c, v);
    *(sh8*)(item_bs + ((size_t)b * S_SZ + row) * D_SZ + c * 8) = v;
  }
  if (tid < 64) {   // zero-pad rows 200..207
    sh8 z = {0,0,0,0,0,0,0,0};
    stsw(Hs, S_SZ + (tid >> 3), tid & 7, z);
  }
  __syncthreads();

  const int w = tid >> 6, l = tid & 63;
  const int lr = l & 15, lg = l >> 4;
  float pvA[8], pvB[8];
  #pragma unroll
  for (int j = 0; j < 8; j++) { pvA[j] = pS[lg * 8 + j]; pvB[j] = pS[32 + lg * 8 + j]; }

  float* outb = adj + (size_t)b * S_SZ * S_SZ;
  for (int mt = 0; mt < 13; mt++) {
    const int arow = mt * 16 + lr;
    const sh8 r0 = ldsr(Hs, arow, lg * 8);
    const sh8 r1 = ldsr(Hs, arow, 32 + lg * 8);
    sh8 h0, h1;
    #pragma unroll
    for (int j = 0; j < 8; j++) {
      h0[j] = (short)f2bf(bf2f((u16)r0[j]) * pvA[j]);
      h1[j] = (short)f2bf(bf2f((u16)r1[j]) * pvB[j]);
    }
    const bf16x8 a0 = __builtin_bit_cast(bf16x8, h0);
    const bf16x8 a1 = __builtin_bit_cast(bf16x8, h1);
    for (int nt = w; nt < 13; nt += 4) {
      const int brow = nt * 16 + lr;
      const bf16x8 b0 = ldsw(Hs, brow, lg * 8);
      const bf16x8 b1 = ldsw(Hs, brow, 32 + lg * 8);
      f32x4 acc = {0.f, 0.f, 0.f, 0.f};
      acc = __builtin_amdgcn_mfma_f32_16x16x32_bf16(a0, b0, acc, 0, 0, 0);
      acc = __builtin_amdgcn_mfma_f32_16x16x32_bf16(a1, b1, acc, 0, 0, 0);
      const int n = nt * 16 + lr;
      const float mj = Ms[n];
      #pragma unroll
      for (int r = 0; r < 4; r++) {
        const int m = mt * 16 + lg * 4 + r;
        if (m < S_SZ && n < S_SZ) {
          const float sg = 1.f / (1.f + __expf(-acc[r]));
          outb[(size_t)m * S_SZ + n] = sg * Ms[m] * mj;
        }
      }
    }
  }
}

// ---------------- K3: hat via MFMA, bf16 output ----------------
// hat[b,kc,s,d] = sum_k item[b,s,k] * W[s, kc*64+d, k]
__global__ __launch_bounds__(256, 4) void hat_mfma(
    const u16* __restrict__ item_bs, const u16* __restrict__ Wb,
    u16* __restrict__ hatb)
{
  const int s  = blockIdx.y;
  const int b0 = blockIdx.x * 64;
  __shared__ u16 As[64 * 64];     // item rows (A-side), 8 KB
  __shared__ u16 Ws_[256 * 64];   // W[s] (B-side), 32 KB
  const int tid = threadIdx.x;

  for (int idx = tid; idx < 64 * 8; idx += 256) {
    const int row = idx >> 3, c = idx & 7;
    const sh8 v = *(const sh8*)(item_bs + ((size_t)(b0 + row) * S_SZ + s) * D_SZ + c * 8);
    stsw(As, row, c, v);
  }
  for (int idx = tid; idx < 256 * 8; idx += 256) {
    const int row = idx >> 3, c = idx & 7;
    const sh8 v = *(const sh8*)(Wb + ((size_t)s * E_SZ + row) * D_SZ + c * 8);
    stsw(Ws_, row, c, v);
  }
  __syncthreads();

  const int w = tid >> 6, l = tid & 63;
  const int lr = l & 15, lg = l >> 4;

  f32x4 acc[4][4];
  #pragma unroll
  for (int mt = 0; mt < 4; mt++)
    #pragma unroll
    for (int nt = 0; nt < 4; nt++) acc[mt][nt] = (f32x4){0.f, 0.f, 0.f, 0.f};

  #pragma unroll
  for (int ks = 0; ks < 2; ks++) {
    bf16x8 af[4], bf_[4];
    #pragma unroll
    for (int mt = 0; mt < 4; mt++)
      af[mt] = ldsw(As, mt * 16 + lr, ks * 32 + lg * 8);
    #pragma unroll
    for (int nt = 0; nt < 4; nt++)
      bf_[nt] = ldsw(Ws_, w * 64 + nt * 16 + lr, ks * 32 + lg * 8);
    #pragma unroll
    for (int mt = 0; mt < 4; mt++)
      #pragma unroll
      for (int nt = 0; nt < 4; nt++)
        acc[mt][nt] = __builtin_amdgcn_mfma_f32_16x16x32_bf16(af[mt], bf_[nt], acc[mt][nt], 0, 0, 0);
  }

  // e = w*64 + nt*16 + lr  ->  kc = w, d = nt*16 + lr
  #pragma unroll
  for (int mt = 0; mt < 4; mt++) {
    #pragma unroll
    for (int r = 0; r < 4; r++) {
      const int bb = b0 + mt * 16 + lg * 4 + r;
      u16* dst = hatb + (((size_t)bb * NI_SZ + w) * S_SZ + s) * D_SZ;
      #pragma unroll
      for (int nt = 0; nt < 4; nt++)
        dst[nt * 16 + lr] = f2bf(acc[mt][nt][r]);
    }
  }
}

// ---------------- K4: dynamic routing (bf16 hat, register-resident) ----------------
__device__ __forceinline__ float rlane(float v, int l) {
  return __int_as_float(__builtin_amdgcn_readlane(__float_as_int(v), l));
}

__global__ __launch_bounds__(1024, 4) void route_kernel(
    const u16* __restrict__ hatb, const float* __restrict__ mask,
    float* __restrict__ out)
{
  const int b = blockIdx.x;
  const int t = threadIdx.x;
  const int w = t >> 6, lane = t & 63;
  const int k = w >> 2, q = w & 3;
  __shared__ float cwS[NI_SZ][212];
  __shared__ float partS[NI_SZ][4][D_SZ];

  const float msv = (lane < 50) ? mask[b * S_SZ + q * 50 + lane] : 0.f;

  float hr[50];
  const u16* hg = hatb + (((size_t)b * NI_SZ + k) * S_SZ + q * 50) * D_SZ + lane;
  #pragma unroll
  for (int j = 0; j < 50; j++) hr[j] = bf2f(hg[j * D_SZ]);
  #pragma unroll
  for (int j = 0; j < 50; j++) asm volatile("" : "+v"(hr[j]));

  const int jj = __brev(lane) >> 26;

  for (int iter = 0; iter < 3; ++iter) {
    float swv;
    if (iter == 0) {
      swv = 0.25f * msv;
    } else {
      const int sidx = q * 50 + (lane < 50 ? lane : 49);
      const float a0 = cwS[0][sidx], a1 = cwS[1][sidx],
                  a2 = cwS[2][sidx], a3 = cwS[3][sidx];
      const float mx = fmaxf(fmaxf(a0, a1), fmaxf(a2, a3));
      const float e0 = __expf(a0 - mx), e1 = __expf(a1 - mx),
                  e2 = __expf(a2 - mx), e3 = __expf(a3 - mx);
      const float ek = (k == 0) ? e0 : (k == 1) ? e1 : (k == 2) ? e2 : e3;
      const float inv = 1.f / (e0 + e1 + e2 + e3);
      swv = (msv == 0.f) ? 0.f : ek * inv;
    }

    float c0 = 0.f, c1 = 0.f, c2 = 0.f, c3 = 0.f;
    #pragma unroll
    for (int j = 0; j < 48; j += 4) {
      c0 = fmaf(rlane(swv, j + 0), hr[j + 0], c0);
      c1 = fmaf(rlane(swv, j + 1), hr[j + 1], c1);
      c2 = fmaf(rlane(swv, j + 2), hr[j + 2], c2);
      c3 = fmaf(rlane(swv, j + 3), hr[j + 3], c3);
    }
    c0 = fmaf(rlane(swv, 48), hr[48], c0);
    c1 = fmaf(rlane(swv, 49), hr[49], c1);
    partS[k][q][lane] = (c0 + c2) + (c1 + c3);
    __syncthreads();

    const float cap = partS[k][0][lane] + partS[k][1][lane]
                    + partS[k][2][lane] + partS[k][3][lane];
    float n = cap * cap;
    #pragma unroll
    for (int off = 32; off; off >>= 1) n += __shfl_xor(n, off);
    const float f = n / (1.f + n) * rsqrtf(n + 1e-9f);
    const float capd = cap * f;

    if (iter < 2) {
      float p[32];
      {
        const int bit = lane & 1;
        #pragma unroll
        for (int j = 0; j < 32; j++) {
          const float lo = hr[j] * capd;
          const float hi = (j + 32 < 50) ? hr[j + 32] * capd : 0.f;
          const float send = bit ? lo : hi;
          const float keep = bit ? hi : lo;
          p[j] = keep + __shfl_xor(send, 1);
        }
      }
      #pragma unroll
      for (int r = 1; r < 6; r++) {
        const int dist = 1 << r;
        const int half = 32 >> r;
        const int bit = (lane >> r) & 1;
        #pragma unroll
        for (int j = 0; j < 32; j++) {
          if (j < half) {
            const float send = bit ? p[j] : p[j + half];
            const float keep = bit ? p[j + half] : p[j];
            p[j] = keep + __shfl_xor(send, dist);
          }
        }
      }
      if (jj < 50) {
        if (iter == 0) cwS[k][q * 50 + jj] = p[0];
        else           cwS[k][q * 50 + jj] += p[0];
      }
      __syncthreads();
    } else if (q == 0) {
      out[((size_t)b * NI_SZ + k) * D_SZ + lane] = capd;
    }
  }
}

extern "C" void kernel_launch(void* const* d_in, const int* in_sizes, int n_in,
                              void* d_out, int out_size, void* d_ws, size_t ws_size,
                              hipStream_t stream)
{
  const int*   uid     = (const int*)d_in[0];
  const int*   age     = (const int*)d_in[1];
  const int*   gender  = (const int*)d_in[2];
  const int*   occup   = (const int*)d_in[3];
  const int*   mid_his = (const int*)d_in[4];
  const float* mask    = (const float*)d_in[5];
  const float* U       = (const float*)d_in[6];
  const float* AT      = (const float*)d_in[7];
  const float* GT      = (const float*)d_in[8];
  const float* OT      = (const float*)d_in[9];
  const float* ME      = (const float*)d_in[10];
  const float* WC      = (const float*)d_in[11];

  float* out  = (float*)d_out;
  float* adj  = out + B_SZ * NI_SZ * D_SZ;

  char* ws = (char*)d_ws;
  u16*   item_bs = (u16*)ws;                                 // 26.2 MB
  u16*   Wb      = (u16*)(ws + 26214400);                    // 6.55 MB
  u16*   hatb    = (u16*)(ws + 26214400 + 6553600);          // 104.9 MB

  wconv_kernel<<<(S_SZ * E_SZ * D_SZ / 8 + 255) / 256, 256, 0, stream>>>(WC, Wb);
  adj_fused<<<B_SZ, 256, 0, stream>>>(uid, age, gender, occup, U, AT, GT, OT,
                                      mid_his, mask, ME, item_bs, adj);
  hat_mfma<<<dim3(16, S_SZ), 256, 0, stream>>>(item_bs, Wb, hatb);
  route_kernel<<<B_SZ, 1024, 0, stream>>>(hatb, mask, out);
}